// Round 1
// baseline (921.785 us; speedup 1.0000x reference)
//
#include <hip/hip_runtime.h>
#include <hip/hip_bf16.h>

// ---------------------------------------------------------------------------
// MinigridPPOLSTMAgent forward, fp32 baseline.
//   T=128, B=256, N=32768, HID=128, NFLAT=1024, NA=7
// Pipeline:
//   K1 conv_fused : obs[N,7,7,3] -> feat[N,1024]   (c1/c2 staged in LDS only)
//   K2 transpose  : w_ih[512,1024] -> wihT[1024,512]
//   K3 gemm_xproj : xproj[N,512] = feat @ w_ih.T   (128x128 tile, 8x8 micro)
//   K4 lstm       : one block per batch element; w_hh row per thread in VGPRs
//   K5 heads      : out[N,8] = hid @ [actor;critic].T + b
// Workspace (floats): feat 33554432 | xproj 16777216 | wihT 524288 | hid 4194304
//   total 55,050,240 f = 220.2 MB
// ---------------------------------------------------------------------------

#define N_IMG   32768
#define T_LEN   128
#define B_ENV   256
#define HID     128

__device__ __forceinline__ float sigm_(float x) { return 1.0f / (1.0f + __expf(-x)); }
__device__ __forceinline__ float tanh_(float x) { return 2.0f / (1.0f + __expf(-2.0f * x)) - 1.0f; }

// ---------------------------------------------------------------------------
// K1: fused conv stack. Block = 256 thr = 4 waves, 8 images per pass.
//   conv1: lane = (img_half, pix_half, ch16); conv2: lane = (img_half, ch32);
//   conv3: lane = ch64, wave does its 2 images sequentially.
// Weights read through L1 (tiny, hot); activations in LDS, plane reads are
// wave-uniform (2 addrs max) -> broadcast, conflict-free.
// ---------------------------------------------------------------------------
__global__ __launch_bounds__(256, 4) void conv_fused(
    const float* __restrict__ obs,
    const float* __restrict__ w1, const float* __restrict__ b1,
    const float* __restrict__ w2, const float* __restrict__ b2,
    const float* __restrict__ w3, const float* __restrict__ b3,
    float* __restrict__ feat)
{
    __shared__ float s_obs[8 * 148];        // [img][147+pad]
    __shared__ float s_c1[8 * 16 * 36];     // [img][ci][6*6]
    __shared__ float s_c2[8 * 32 * 26];     // [img][ci][25+pad]

    const int tid  = threadIdx.x;
    const int lane = tid & 63;
    const int wv   = tid >> 6;          // wave id 0..3
    const int sub  = lane >> 5;         // image sub (0/1) within wave
    const int ch1  = lane & 15;         // conv1 out channel
    const int h1   = (lane >> 4) & 1;   // conv1 pixel half
    const int co2  = lane & 31;         // conv2 out channel

    // conv1 per-lane weights (12 regs) + biases
    float w1r[12];
#pragma unroll
    for (int ci = 0; ci < 3; ci++)
#pragma unroll
        for (int kk = 0; kk < 4; kk++)
            w1r[ci * 4 + kk] = w1[ch1 * 12 + ci * 4 + kk];
    const float b1v = b1[ch1];
    const float b2v = b2[co2];
    const float b3v = b3[lane];

    for (int base = blockIdx.x * 8; base < N_IMG; base += gridDim.x * 8) {
        // ---- stage obs (8 images x 147 floats), coalesced ----
        for (int i = tid; i < 8 * 147; i += 256) {
            int im = i / 147;
            int r  = i - im * 147;
            s_obs[im * 148 + r] = obs[(size_t)(base + im) * 147 + r];
        }
        __syncthreads();

        // ---- conv1: 7x7x3 -> 6x6x16 ----
        {
            const int img = 2 * wv + sub;
            const float* ob  = &s_obs[img * 148];
            float*       c1p = &s_c1[img * 576 + ch1 * 36];
#pragma unroll
            for (int jj = 0; jj < 18; jj++) {
                const int py = h1 * 3 + jj / 6;
                const int px = jj % 6;
                float a = b1v;
#pragma unroll
                for (int ci = 0; ci < 3; ci++) {
                    a = fmaf(ob[(py * 7 + px) * 3 + ci],           w1r[ci * 4 + 0], a);
                    a = fmaf(ob[(py * 7 + px + 1) * 3 + ci],       w1r[ci * 4 + 1], a);
                    a = fmaf(ob[((py + 1) * 7 + px) * 3 + ci],     w1r[ci * 4 + 2], a);
                    a = fmaf(ob[((py + 1) * 7 + px + 1) * 3 + ci], w1r[ci * 4 + 3], a);
                }
                c1p[h1 * 18 + jj] = fmaxf(a, 0.0f);
            }
        }
        __syncthreads();

        // ---- conv2: 6x6x16 -> 5x5x32 ----
        {
            const int img = 2 * wv + sub;
            const float* c1p = &s_c1[img * 576];
            float acc2[25];
#pragma unroll
            for (int p = 0; p < 25; p++) acc2[p] = b2v;
#pragma unroll
            for (int ci = 0; ci < 16; ci++) {
                float plane[36];
#pragma unroll
                for (int k = 0; k < 36; k++) plane[k] = c1p[ci * 36 + k];
                const float4 w4 = *(const float4*)&w2[(co2 * 16 + ci) * 4];
#pragma unroll
                for (int p = 0; p < 25; p++) {
                    const int py = p / 5, px = p % 5;
                    float a = acc2[p];
                    a = fmaf(plane[py * 6 + px],           w4.x, a);
                    a = fmaf(plane[py * 6 + px + 1],       w4.y, a);
                    a = fmaf(plane[(py + 1) * 6 + px],     w4.z, a);
                    a = fmaf(plane[(py + 1) * 6 + px + 1], w4.w, a);
                    acc2[p] = a;
                }
            }
            float* c2p = &s_c2[img * 832 + co2 * 26];
#pragma unroll
            for (int p = 0; p < 25; p++) c2p[p] = fmaxf(acc2[p], 0.0f);
        }
        __syncthreads();

        // ---- conv3: 5x5x32 -> 4x4x64, lane = out channel ----
#pragma unroll 1
        for (int si = 0; si < 2; si++) {
            const int img = 2 * wv + si;
            const float* c2p = &s_c2[img * 832];
            float acc3[16];
#pragma unroll
            for (int p = 0; p < 16; p++) acc3[p] = b3v;
#pragma unroll
            for (int ci = 0; ci < 32; ci++) {
                float plane[25];
#pragma unroll
                for (int k = 0; k < 25; k++) plane[k] = c2p[ci * 26 + k];
                const float4 w4 = *(const float4*)&w3[(lane * 32 + ci) * 4];
#pragma unroll
                for (int p = 0; p < 16; p++) {
                    const int py = p / 4, px = p % 4;
                    float a = acc3[p];
                    a = fmaf(plane[py * 5 + px],           w4.x, a);
                    a = fmaf(plane[py * 5 + px + 1],       w4.y, a);
                    a = fmaf(plane[(py + 1) * 5 + px],     w4.z, a);
                    a = fmaf(plane[(py + 1) * 5 + px + 1], w4.w, a);
                    acc3[p] = a;
                }
            }
            float* fp = &feat[(size_t)(base + img) * 1024 + lane * 16];
#pragma unroll
            for (int q = 0; q < 4; q++) {
                float4 f4;
                f4.x = fmaxf(acc3[q * 4 + 0], 0.0f);
                f4.y = fmaxf(acc3[q * 4 + 1], 0.0f);
                f4.z = fmaxf(acc3[q * 4 + 2], 0.0f);
                f4.w = fmaxf(acc3[q * 4 + 3], 0.0f);
                *(float4*)&fp[q * 4] = f4;
            }
        }
    }
}

// ---------------------------------------------------------------------------
// K2: w_ih [512,1024] -> wihT [1024,512] (tiny, 2 MB; naive is fine)
// ---------------------------------------------------------------------------
__global__ void transpose_wih(const float* __restrict__ w, float* __restrict__ wt)
{
    const int idx = blockIdx.x * 256 + threadIdx.x;   // < 524288
    const int k = idx >> 9, j = idx & 511;
    wt[idx] = w[j * 1024 + k];
}

// ---------------------------------------------------------------------------
// K3: xproj[M=32768, N=512] = feat[M,1024] @ wihT[1024,512]
//   BM=BN=128, BK=16, 256 thr, 8x8 microtile. As stored [k][m] (stride 132,
//   rows stay 16B aligned: 132*4=528=16*33), Bs [k][n] stride 132.
// ---------------------------------------------------------------------------
__global__ __launch_bounds__(256, 2) void gemm_xproj(
    const float* __restrict__ A, const float* __restrict__ Bt, float* __restrict__ C)
{
    __shared__ float As[16][132];
    __shared__ float Bs[16][132];

    const int tid = threadIdx.x;
    const int bx = blockIdx.x & 3;        // n block (4)
    const int by = blockIdx.x >> 2;       // m block (256)
    const int m0 = by * 128, n0 = bx * 128;
    const int tx = tid & 15, ty = tid >> 4;

    const int arow = tid >> 2, akq = tid & 3;   // A: 64 rows x 4 k-quads per iter
    const int bk = tid >> 5, bnq = tid & 31;    // B: 8 k x 32 n-quads per iter

    float acc[8][8];
#pragma unroll
    for (int i = 0; i < 8; i++)
#pragma unroll
        for (int j = 0; j < 8; j++) acc[i][j] = 0.0f;

    for (int k0 = 0; k0 < 1024; k0 += 16) {
#pragma unroll
        for (int i = 0; i < 2; i++) {
            const int m = arow + 64 * i;
            const float4 v = *(const float4*)&A[(size_t)(m0 + m) * 1024 + k0 + akq * 4];
            As[akq * 4 + 0][m] = v.x;
            As[akq * 4 + 1][m] = v.y;
            As[akq * 4 + 2][m] = v.z;
            As[akq * 4 + 3][m] = v.w;
        }
#pragma unroll
        for (int i = 0; i < 2; i++) {
            const int k = bk + 8 * i;
            const float4 v = *(const float4*)&Bt[(size_t)(k0 + k) * 512 + n0 + bnq * 4];
            *(float4*)&Bs[k][bnq * 4] = v;
        }
        __syncthreads();

#pragma unroll
        for (int kk = 0; kk < 16; kk++) {
            float a[8], b[8];
            *(float4*)&a[0] = *(const float4*)&As[kk][ty * 8];
            *(float4*)&a[4] = *(const float4*)&As[kk][ty * 8 + 4];
            *(float4*)&b[0] = *(const float4*)&Bs[kk][tx * 8];
            *(float4*)&b[4] = *(const float4*)&Bs[kk][tx * 8 + 4];
#pragma unroll
            for (int i = 0; i < 8; i++)
#pragma unroll
                for (int j = 0; j < 8; j++)
                    acc[i][j] = fmaf(a[i], b[j], acc[i][j]);
        }
        __syncthreads();
    }

#pragma unroll
    for (int i = 0; i < 8; i++) {
        float4 v0, v1;
        v0.x = acc[i][0]; v0.y = acc[i][1]; v0.z = acc[i][2]; v0.w = acc[i][3];
        v1.x = acc[i][4]; v1.y = acc[i][5]; v1.z = acc[i][6]; v1.w = acc[i][7];
        float* cp = &C[(size_t)(m0 + ty * 8 + i) * 512 + n0 + tx * 8];
        *(float4*)&cp[0] = v0;
        *(float4*)&cp[4] = v1;
    }
}

// ---------------------------------------------------------------------------
// K4: LSTM scan. Block b = batch element b; 512 threads, thread j owns gate j
//   (w_hh row j in 128 VGPRs). h broadcast via LDS (wave-uniform reads).
//   Gate order i,f,g,o in blocks of 128. 2 barriers/step.
// ---------------------------------------------------------------------------
__global__ __launch_bounds__(512, 2) void lstm_kernel(
    const float* __restrict__ xproj, const float* __restrict__ done,
    const float* __restrict__ h0, const float* __restrict__ c0,
    const float* __restrict__ w_hh,
    const float* __restrict__ b_ih, const float* __restrict__ b_hh,
    float* __restrict__ hid, float* __restrict__ out)
{
    const int b = blockIdx.x;
    const int j = threadIdx.x;

    __shared__ __align__(16) float h_s[HID];
    __shared__ float a_s[512];

    float w[128];
    const float4* wrow = (const float4*)(w_hh + (size_t)j * 128);
#pragma unroll
    for (int q = 0; q < 32; q++) {
        const float4 v = wrow[q];
        w[q * 4 + 0] = v.x; w[q * 4 + 1] = v.y; w[q * 4 + 2] = v.z; w[q * 4 + 3] = v.w;
    }
    const float bias = b_ih[j] + b_hh[j];

    float h = 0.0f, c = 0.0f;
    if (j < HID) { h = h0[b * HID + j]; c = c0[b * HID + j]; }

    float xp = xproj[(size_t)b * 512 + j];   // prefetch t = 0

    for (int t = 0; t < T_LEN; t++) {
        if (j < HID) {
            const float m = 1.0f - done[t * B_ENV + b];
            h *= m; c *= m;
            h_s[j] = h;
        }
        __syncthreads();

        float g = bias + xp;
#pragma unroll
        for (int q = 0; q < 32; q++) {
            const float4 hv = *(const float4*)&h_s[q * 4];
            g = fmaf(w[q * 4 + 0], hv.x, g);
            g = fmaf(w[q * 4 + 1], hv.y, g);
            g = fmaf(w[q * 4 + 2], hv.z, g);
            g = fmaf(w[q * 4 + 3], hv.w, g);
        }
        if (t < T_LEN - 1) xp = xproj[((size_t)(t + 1) * B_ENV + b) * 512 + j];

        const float a = (j >= 256 && j < 384) ? tanh_(g) : sigm_(g);
        a_s[j] = a;
        __syncthreads();

        if (j < HID) {
            const float ig = a_s[j], fg = a_s[j + 128], gg = a_s[j + 256], og = a_s[j + 384];
            c = fmaf(fg, c, ig * gg);
            h = og * tanh_(c);
            hid[((size_t)t * B_ENV + b) * HID + j] = h;
        }
    }

    if (j < HID) {
        out[262144 + b * HID + j] = h;   // hT at N*8
        out[294912 + b * HID + j] = c;   // cT at N*8 + B*HID
    }
}

// ---------------------------------------------------------------------------
// K5: heads. out[n][0..6] = actor, out[n][7] = critic. 32 rows / block.
// ---------------------------------------------------------------------------
__global__ __launch_bounds__(256, 2) void heads_kernel(
    const float* __restrict__ hid,
    const float* __restrict__ aw, const float* __restrict__ ab,
    const float* __restrict__ cw, const float* __restrict__ cb,
    float* __restrict__ out)
{
    __shared__ float hs[32 * 129];
    __shared__ float ws[8 * 130];
    __shared__ float bs[8];

    const int tid = threadIdx.x;
    const int n0 = blockIdx.x * 32;

    for (int i = tid; i < 1024; i += 256) {
        const int r = i >> 7, k = i & 127;
        ws[r * 130 + k] = (r < 7) ? aw[r * 128 + k] : cw[k];
    }
    if (tid < 8) bs[tid] = (tid < 7) ? ab[tid] : cb[0];
    for (int i = tid; i < 4096; i += 256) {
        const int r = i >> 7, k = i & 127;
        hs[r * 129 + k] = hid[(size_t)(n0 + r) * 128 + k];
    }
    __syncthreads();

    const int r = tid >> 3, jj = tid & 7;
    float acc = bs[jj];
    const float* hp = &hs[r * 129];
    const float* wp = &ws[jj * 130];
#pragma unroll
    for (int k = 0; k < 128; k++) acc = fmaf(hp[k], wp[k], acc);
    out[(size_t)(n0 + r) * 8 + jj] = acc;
}

// ---------------------------------------------------------------------------
extern "C" void kernel_launch(void* const* d_in, const int* in_sizes, int n_in,
                              void* d_out, int out_size, void* d_ws, size_t ws_size,
                              hipStream_t stream)
{
    (void)in_sizes; (void)n_in; (void)out_size; (void)ws_size;

    const float* obs  = (const float*)d_in[0];
    const float* done = (const float*)d_in[1];
    const float* h0   = (const float*)d_in[2];
    const float* c0   = (const float*)d_in[3];
    const float* w1   = (const float*)d_in[4];
    const float* b1   = (const float*)d_in[5];
    const float* w2   = (const float*)d_in[6];
    const float* b2   = (const float*)d_in[7];
    const float* w3   = (const float*)d_in[8];
    const float* b3   = (const float*)d_in[9];
    const float* w_ih = (const float*)d_in[10];
    const float* w_hh = (const float*)d_in[11];
    const float* b_ih = (const float*)d_in[12];
    const float* b_hh = (const float*)d_in[13];
    const float* aw   = (const float*)d_in[14];
    const float* ab   = (const float*)d_in[15];
    const float* cw   = (const float*)d_in[16];
    const float* cb   = (const float*)d_in[17];
    float* out = (float*)d_out;

    float* feat  = (float*)d_ws;                 // 33,554,432 f
    float* xproj = feat  + 33554432ull;          // 16,777,216 f
    float* wihT  = xproj + 16777216ull;          //    524,288 f
    float* hid   = wihT  + 524288ull;            //  4,194,304 f

    conv_fused<<<1024, 256, 0, stream>>>(obs, w1, b1, w2, b2, w3, b3, feat);
    transpose_wih<<<2048, 256, 0, stream>>>(w_ih, wihT);
    gemm_xproj<<<1024, 256, 0, stream>>>(feat, wihT, xproj);
    lstm_kernel<<<256, 512, 0, stream>>>(xproj, done, h0, c0, w_hh, b_ih, b_hh, hid, out);
    heads_kernel<<<1024, 256, 0, stream>>>(hid, aw, ab, cw, cb, out);
}

// Round 2
// 645.637 us; speedup vs baseline: 1.4277x; 1.4277x over previous
//
#include <hip/hip_runtime.h>
#include <hip/hip_bf16.h>

// ---------------------------------------------------------------------------
// MinigridPPOLSTMAgent forward, round 2: bf16-MFMA xproj GEMM (m97 structure).
//   T=128, B=256, N=32768, HID=128, NFLAT=1024, NA=7
// Pipeline:
//   K1 conv_fused : obs[N,7,7,3] -> featb[N,1024] (bf16; c1/c2 in LDS only)
//   K2 cast_wih   : w_ih fp32 [512,1024] -> bf16 (same layout; GEMM is B^T form)
//   K3 gemm_mfma  : xproj[N,512] = feat @ w_ih.T  (128x128 tile, BK=32,
//                   mfma_f32_16x16x32_bf16, global_load_lds width=16)
//   K4 lstm       : block b = batch elem; w_hh row/thread in VGPRs; 4-way acc
//   K5 heads      : out[N,8] = hid @ [actor;critic].T + b
// Workspace: featb 64MB | wb 1MB | xproj 64MB | hid 16MB  = 145 MB
// ---------------------------------------------------------------------------

#define N_IMG   32768
#define T_LEN   128
#define B_ENV   256
#define HID     128

typedef __bf16 bf16x8 __attribute__((ext_vector_type(8)));
typedef float  f32x4  __attribute__((ext_vector_type(4)));
typedef unsigned short ushort8v __attribute__((ext_vector_type(8)));
typedef unsigned short ushort4v __attribute__((ext_vector_type(4)));

__device__ __forceinline__ float sigm_(float x) { return 1.0f / (1.0f + __expf(-x)); }
__device__ __forceinline__ float tanh_(float x) { return 2.0f / (1.0f + __expf(-2.0f * x)) - 1.0f; }

// fp32 -> bf16 round-to-nearest-even (finite inputs)
__device__ __forceinline__ unsigned short f2bf(float x) {
    union { float f; unsigned int u; } un; un.f = x;
    const unsigned int r = un.u + 0x7fffu + ((un.u >> 16) & 1u);
    return (unsigned short)(r >> 16);
}

#define GLDS16(g, l) __builtin_amdgcn_global_load_lds( \
    (const __attribute__((address_space(1))) unsigned int*)(g), \
    (__attribute__((address_space(3))) unsigned int*)(l), 16, 0, 0)

// ---------------------------------------------------------------------------
// K1: fused conv stack, feat out in bf16. Block = 256 thr, 8 images per pass.
// ---------------------------------------------------------------------------
__global__ __launch_bounds__(256, 4) void conv_fused(
    const float* __restrict__ obs,
    const float* __restrict__ w1, const float* __restrict__ b1,
    const float* __restrict__ w2, const float* __restrict__ b2,
    const float* __restrict__ w3, const float* __restrict__ b3,
    unsigned short* __restrict__ featb)
{
    __shared__ float s_obs[8 * 148];        // [img][147+pad]
    __shared__ float s_c1[8 * 16 * 36];     // [img][ci][6*6]   (36 % 4 == 0)
    __shared__ float s_c2[8 * 32 * 28];     // [img][ci][25+pad] (28 % 4 == 0)

    const int tid  = threadIdx.x;
    const int lane = tid & 63;
    const int wv   = tid >> 6;
    const int sub  = lane >> 5;
    const int ch1  = lane & 15;
    const int h1   = (lane >> 4) & 1;
    const int co2  = lane & 31;

    float w1r[12];
#pragma unroll
    for (int ci = 0; ci < 3; ci++)
#pragma unroll
        for (int kk = 0; kk < 4; kk++)
            w1r[ci * 4 + kk] = w1[ch1 * 12 + ci * 4 + kk];
    const float b1v = b1[ch1];
    const float b2v = b2[co2];
    const float b3v = b3[lane];

    for (int base = blockIdx.x * 8; base < N_IMG; base += gridDim.x * 8) {
        for (int i = tid; i < 8 * 147; i += 256) {
            int im = i / 147;
            int r  = i - im * 147;
            s_obs[im * 148 + r] = obs[(size_t)(base + im) * 147 + r];
        }
        __syncthreads();

        // ---- conv1: 7x7x3 -> 6x6x16 ----
        {
            const int img = 2 * wv + sub;
            const float* ob  = &s_obs[img * 148];
            float*       c1p = &s_c1[img * 576 + ch1 * 36];
#pragma unroll
            for (int jj = 0; jj < 18; jj++) {
                const int py = h1 * 3 + jj / 6;
                const int px = jj % 6;
                float a = b1v;
#pragma unroll
                for (int ci = 0; ci < 3; ci++) {
                    a = fmaf(ob[(py * 7 + px) * 3 + ci],           w1r[ci * 4 + 0], a);
                    a = fmaf(ob[(py * 7 + px + 1) * 3 + ci],       w1r[ci * 4 + 1], a);
                    a = fmaf(ob[((py + 1) * 7 + px) * 3 + ci],     w1r[ci * 4 + 2], a);
                    a = fmaf(ob[((py + 1) * 7 + px + 1) * 3 + ci], w1r[ci * 4 + 3], a);
                }
                c1p[h1 * 18 + jj] = fmaxf(a, 0.0f);
            }
        }
        __syncthreads();

        // ---- conv2: 6x6x16 -> 5x5x32 (plane via float4 ds_read_b128) ----
        {
            const int img = 2 * wv + sub;
            const float* c1p = &s_c1[img * 576];
            float acc2[25];
#pragma unroll
            for (int p = 0; p < 25; p++) acc2[p] = b2v;
#pragma unroll
            for (int ci = 0; ci < 16; ci++) {
                float plane[36];
#pragma unroll
                for (int q = 0; q < 9; q++)
                    *(float4*)&plane[q * 4] = *(const float4*)&c1p[ci * 36 + q * 4];
                const float4 w4 = *(const float4*)&w2[(co2 * 16 + ci) * 4];
#pragma unroll
                for (int p = 0; p < 25; p++) {
                    const int py = p / 5, px = p % 5;
                    float a = acc2[p];
                    a = fmaf(plane[py * 6 + px],           w4.x, a);
                    a = fmaf(plane[py * 6 + px + 1],       w4.y, a);
                    a = fmaf(plane[(py + 1) * 6 + px],     w4.z, a);
                    a = fmaf(plane[(py + 1) * 6 + px + 1], w4.w, a);
                    acc2[p] = a;
                }
            }
            float* c2p = &s_c2[img * 896 + co2 * 28];
#pragma unroll
            for (int p = 0; p < 25; p++) c2p[p] = fmaxf(acc2[p], 0.0f);
        }
        __syncthreads();

        // ---- conv3: 5x5x32 -> 4x4x64, lane = out channel ----
#pragma unroll 1
        for (int si = 0; si < 2; si++) {
            const int img = 2 * wv + si;
            const float* c2p = &s_c2[img * 896];
            float acc3[16];
#pragma unroll
            for (int p = 0; p < 16; p++) acc3[p] = b3v;
#pragma unroll
            for (int ci = 0; ci < 32; ci++) {
                float plane[25];
#pragma unroll
                for (int q = 0; q < 6; q++)
                    *(float4*)&plane[q * 4] = *(const float4*)&c2p[ci * 28 + q * 4];
                plane[24] = c2p[ci * 28 + 24];
                const float4 w4 = *(const float4*)&w3[(lane * 32 + ci) * 4];
#pragma unroll
                for (int p = 0; p < 16; p++) {
                    const int py = p / 4, px = p % 4;
                    float a = acc3[p];
                    a = fmaf(plane[py * 5 + px],           w4.x, a);
                    a = fmaf(plane[py * 5 + px + 1],       w4.y, a);
                    a = fmaf(plane[(py + 1) * 5 + px],     w4.z, a);
                    a = fmaf(plane[(py + 1) * 5 + px + 1], w4.w, a);
                    acc3[p] = a;
                }
            }
            unsigned short fb[16];
#pragma unroll
            for (int p = 0; p < 16; p++) fb[p] = f2bf(fmaxf(acc3[p], 0.0f));
            unsigned short* fp = &featb[(size_t)(base + img) * 1024 + lane * 16];
            *(ushort8v*)&fp[0] = *(ushort8v*)&fb[0];
            *(ushort8v*)&fp[8] = *(ushort8v*)&fb[8];
        }
        __syncthreads();
    }
}

// ---------------------------------------------------------------------------
// K2: w_ih [512,1024] fp32 -> bf16, same layout (no transpose needed)
// ---------------------------------------------------------------------------
__global__ void cast_wih(const float* __restrict__ w, unsigned short* __restrict__ wb)
{
    const int idx = (blockIdx.x * 256 + threadIdx.x) * 4;   // 512 blocks
    const float4 v = *(const float4*)&w[idx];
    ushort4v u;
    u.x = f2bf(v.x); u.y = f2bf(v.y); u.z = f2bf(v.z); u.w = f2bf(v.w);
    *(ushort4v*)&wb[idx] = u;
}

// ---------------------------------------------------------------------------
// K3: xproj[32768,512] = A[32768,1024]_bf16 @ W[512,1024]_bf16^T  (fp32 out)
//   m97 structure: 128x128 tile, BK=32, 4 waves (2x2), 4x4 16x16x32 MFMAs,
//   global_load_lds width=16, 2-barrier K-loop.
// ---------------------------------------------------------------------------
__global__ __launch_bounds__(256, 2) void gemm_xproj_mfma(
    const unsigned short* __restrict__ A,
    const unsigned short* __restrict__ W,
    float* __restrict__ C)
{
    __shared__ unsigned short As[128 * 32];   // [m][k] row-major, 8 KB
    __shared__ unsigned short Bs[128 * 32];   // [n][k] row-major, 8 KB

    const int tid  = threadIdx.x;
    const int bx = blockIdx.x & 3;            // n block (4)
    const int by = blockIdx.x >> 2;           // m block (256)
    const int m0 = by * 128, n0 = bx * 128;
    const int lane = tid & 63, wave = tid >> 6;
    const int wm = (wave >> 1) * 64, wn = (wave & 1) * 64;
    const int srow = tid >> 2, sseg = tid & 3;    // staging: 64 rows x 4 segs

    const unsigned short* Ag = A + (size_t)(m0 + srow) * 1024 + sseg * 8;
    const unsigned short* Wg = W + (size_t)(n0 + srow) * 1024 + sseg * 8;

    f32x4 acc[4][4];
#pragma unroll
    for (int i = 0; i < 4; i++)
#pragma unroll
        for (int j = 0; j < 4; j++) acc[i][j] = (f32x4){0.f, 0.f, 0.f, 0.f};

    const int fr = lane & 15, fq = lane >> 4;

    for (int k0 = 0; k0 < 1024; k0 += 32) {
        __syncthreads();                              // prev-iter LDS reads done
        GLDS16(Ag + k0,             (char*)As + tid * 16);
        GLDS16(Ag + k0 + 64 * 1024, (char*)As + tid * 16 + 4096);
        GLDS16(Wg + k0,             (char*)Bs + tid * 16);
        GLDS16(Wg + k0 + 64 * 1024, (char*)Bs + tid * 16 + 4096);
        __syncthreads();                              // compiler drains vmcnt here

        bf16x8 af[4], bfv[4];
#pragma unroll
        for (int i = 0; i < 4; i++)
            af[i] = *(const bf16x8*)&As[(wm + i * 16 + fr) * 32 + fq * 8];
#pragma unroll
        for (int j = 0; j < 4; j++)
            bfv[j] = *(const bf16x8*)&Bs[(wn + j * 16 + fr) * 32 + fq * 8];
#pragma unroll
        for (int i = 0; i < 4; i++)
#pragma unroll
            for (int j = 0; j < 4; j++)
                acc[i][j] = __builtin_amdgcn_mfma_f32_16x16x32_bf16(af[i], bfv[j], acc[i][j], 0, 0, 0);
    }

    // epilogue: C/D layout col=lane&15, row=(lane>>4)*4+reg  [m89/m91]
    const int cr = fq * 4, cc = fr;
#pragma unroll
    for (int i = 0; i < 4; i++) {
#pragma unroll
        for (int j = 0; j < 4; j++) {
            float* cp = &C[(size_t)(m0 + wm + i * 16 + cr) * 512 + (n0 + wn + j * 16 + cc)];
#pragma unroll
            for (int r = 0; r < 4; r++)
                cp[(size_t)r * 512] = acc[i][j][r];
        }
    }
}

// ---------------------------------------------------------------------------
// K4: LSTM scan. Block b = batch element; 512 thr, thread j owns gate row j.
//   4-way accumulators (break fmaf dep chain); done/xproj prefetched.
// ---------------------------------------------------------------------------
__global__ __launch_bounds__(512, 2) void lstm_kernel(
    const float* __restrict__ xproj, const float* __restrict__ done,
    const float* __restrict__ h0, const float* __restrict__ c0,
    const float* __restrict__ w_hh,
    const float* __restrict__ b_ih, const float* __restrict__ b_hh,
    float* __restrict__ hid, float* __restrict__ out)
{
    const int b = blockIdx.x;
    const int j = threadIdx.x;

    __shared__ __align__(16) float h_s[HID];
    __shared__ float a_s[512];

    float w[128];
    const float4* wrow = (const float4*)(w_hh + (size_t)j * 128);
#pragma unroll
    for (int q = 0; q < 32; q++) {
        const float4 v = wrow[q];
        w[q * 4 + 0] = v.x; w[q * 4 + 1] = v.y; w[q * 4 + 2] = v.z; w[q * 4 + 3] = v.w;
    }
    const float bias = b_ih[j] + b_hh[j];

    float h = 0.0f, c = 0.0f;
    if (j < HID) { h = h0[b * HID + j]; c = c0[b * HID + j]; }

    float xp   = xproj[(size_t)b * 512 + j];   // prefetch t = 0
    float dcur = done[b];                       // prefetch t = 0

    for (int t = 0; t < T_LEN; t++) {
        if (j < HID) {
            const float m = 1.0f - dcur;
            h *= m; c *= m;
            h_s[j] = h;
        }
        __syncthreads();

        float g0 = bias + xp, g1 = 0.0f, g2 = 0.0f, g3 = 0.0f;
#pragma unroll
        for (int q = 0; q < 32; q++) {
            const float4 hv = *(const float4*)&h_s[q * 4];
            g0 = fmaf(w[q * 4 + 0], hv.x, g0);
            g1 = fmaf(w[q * 4 + 1], hv.y, g1);
            g2 = fmaf(w[q * 4 + 2], hv.z, g2);
            g3 = fmaf(w[q * 4 + 3], hv.w, g3);
        }
        const float g = (g0 + g1) + (g2 + g3);
        if (t < T_LEN - 1) {
            xp   = xproj[((size_t)(t + 1) * B_ENV + b) * 512 + j];
            dcur = done[(t + 1) * B_ENV + b];
        }

        const float a = (j >= 256 && j < 384) ? tanh_(g) : sigm_(g);
        a_s[j] = a;
        __syncthreads();

        if (j < HID) {
            const float ig = a_s[j], fg = a_s[j + 128], gg = a_s[j + 256], og = a_s[j + 384];
            c = fmaf(fg, c, ig * gg);
            h = og * tanh_(c);
            hid[((size_t)t * B_ENV + b) * HID + j] = h;
        }
    }

    if (j < HID) {
        out[262144 + b * HID + j] = h;   // hT at N*8
        out[294912 + b * HID + j] = c;   // cT at N*8 + B*HID
    }
}

// ---------------------------------------------------------------------------
// K5: heads. out[n][0..6] = actor, out[n][7] = critic. 32 rows / block.
// ---------------------------------------------------------------------------
__global__ __launch_bounds__(256, 2) void heads_kernel(
    const float* __restrict__ hid,
    const float* __restrict__ aw, const float* __restrict__ ab,
    const float* __restrict__ cw, const float* __restrict__ cb,
    float* __restrict__ out)
{
    __shared__ float hs[32 * 129];
    __shared__ float ws[8 * 130];
    __shared__ float bs[8];

    const int tid = threadIdx.x;
    const int n0 = blockIdx.x * 32;

    for (int i = tid; i < 1024; i += 256) {
        const int r = i >> 7, k = i & 127;
        ws[r * 130 + k] = (r < 7) ? aw[r * 128 + k] : cw[k];
    }
    if (tid < 8) bs[tid] = (tid < 7) ? ab[tid] : cb[0];
    for (int i = tid; i < 4096; i += 256) {
        const int r = i >> 7, k = i & 127;
        hs[r * 129 + k] = hid[(size_t)(n0 + r) * 128 + k];
    }
    __syncthreads();

    const int r = tid >> 3, jj = tid & 7;
    float acc = bs[jj];
    const float* hp = &hs[r * 129];
    const float* wp = &ws[jj * 130];
#pragma unroll
    for (int k = 0; k < 128; k++) acc = fmaf(hp[k], wp[k], acc);
    out[(size_t)(n0 + r) * 8 + jj] = acc;
}

// ---------------------------------------------------------------------------
extern "C" void kernel_launch(void* const* d_in, const int* in_sizes, int n_in,
                              void* d_out, int out_size, void* d_ws, size_t ws_size,
                              hipStream_t stream)
{
    (void)in_sizes; (void)n_in; (void)out_size; (void)ws_size;

    const float* obs  = (const float*)d_in[0];
    const float* done = (const float*)d_in[1];
    const float* h0   = (const float*)d_in[2];
    const float* c0   = (const float*)d_in[3];
    const float* w1   = (const float*)d_in[4];
    const float* b1   = (const float*)d_in[5];
    const float* w2   = (const float*)d_in[6];
    const float* b2   = (const float*)d_in[7];
    const float* w3   = (const float*)d_in[8];
    const float* b3   = (const float*)d_in[9];
    const float* w_ih = (const float*)d_in[10];
    const float* w_hh = (const float*)d_in[11];
    const float* b_ih = (const float*)d_in[12];
    const float* b_hh = (const float*)d_in[13];
    const float* aw   = (const float*)d_in[14];
    const float* ab   = (const float*)d_in[15];
    const float* cw   = (const float*)d_in[16];
    const float* cb   = (const float*)d_in[17];
    float* out = (float*)d_out;

    unsigned short* featb = (unsigned short*)d_ws;          // 33,554,432 bf16 = 64 MB
    unsigned short* wb    = featb + 33554432ull;            //    524,288 bf16 =  1 MB
    float* xproj = (float*)(wb + 524288ull);                // 16,777,216 f32  = 64 MB
    float* hid   = xproj + 16777216ull;                     //  4,194,304 f32  = 16 MB

    conv_fused<<<4096, 256, 0, stream>>>(obs, w1, b1, w2, b2, w3, b3, featb);
    cast_wih<<<512, 256, 0, stream>>>(w_ih, wb);
    gemm_xproj_mfma<<<1024, 256, 0, stream>>>(featb, wb, xproj);
    lstm_kernel<<<256, 512, 0, stream>>>(xproj, done, h0, c0, w_hh, b_ih, b_hh, hid, out);
    heads_kernel<<<1024, 256, 0, stream>>>(hid, aw, ab, cw, cb, out);
}

// Round 3
// 349.118 us; speedup vs baseline: 2.6403x; 1.8493x over previous
//
#include <hip/hip_runtime.h>
#include <hip/hip_bf16.h>

// ---------------------------------------------------------------------------
// MinigridPPOLSTMAgent forward, round 3: MFMA conv2/conv3 + fp16 everywhere.
//   T=128, B=256, N=32768, HID=128, NFLAT=1024, NA=7
// Pipeline:
//   P1 prep_wih   : w_ih fp32 [512][co*16+p] -> fp16 wb[512][p*64+co] (K-perm)
//   P2 prep_convw : w2/w3 -> MFMA A-fragment-ordered fp16 tables
//   K1 conv_fused : obs -> featb[N][p*64+co] fp16.  conv1 VALU; conv2/conv3
//                   MFMA 16x16x32 f16 (M=co, N=16 imgs, K=pos-chained)
//   K3 gemm_mfma  : xproj[N,512] = featb @ wb^T (128x128 tile, BK=32)
//   K4 lstm       : block b = batch elem; w_hh row/thread in VGPRs
//   K5 heads      : out[N,8] = hid @ [actor;critic].T + b
// ---------------------------------------------------------------------------

#define N_IMG   32768
#define T_LEN   128
#define B_ENV   256
#define HID     128

typedef _Float16 f16x8 __attribute__((ext_vector_type(8)));
typedef float    f32x4 __attribute__((ext_vector_type(4)));
typedef unsigned short ushort8v __attribute__((ext_vector_type(8)));
typedef unsigned short ushort4v __attribute__((ext_vector_type(4)));

__device__ __forceinline__ float sigm_(float x) { return 1.0f / (1.0f + __expf(-x)); }
__device__ __forceinline__ float tanh_(float x) { return 2.0f / (1.0f + __expf(-2.0f * x)) - 1.0f; }

__device__ __forceinline__ unsigned short f2h(float x) {
    _Float16 h = (_Float16)x;
    union { _Float16 h; unsigned short u; } un; un.h = h;
    return un.u;
}

#define GLDS16(g, l) __builtin_amdgcn_global_load_lds( \
    (const __attribute__((address_space(1))) unsigned int*)(g), \
    (__attribute__((address_space(3))) unsigned int*)(l), 16, 0, 0)

// ---------------------------------------------------------------------------
// P1: w_ih fp32 [n][k=co*16+p] -> fp16 wb[n][k'=p*64+co]
//   (same K-permutation the conv kernel uses for feat rows -> GEMM unchanged)
// ---------------------------------------------------------------------------
__global__ void prep_wih(const float* __restrict__ w, unsigned short* __restrict__ wb)
{
    const int idx = blockIdx.x * 256 + threadIdx.x;   // < 524288
    const int n = idx >> 10, kk = idx & 1023;
    const int p = kk >> 6, co = kk & 63;
    wb[idx] = f2h(w[n * 1024 + co * 16 + p]);
}

// ---------------------------------------------------------------------------
// P2: conv2/conv3 weight -> MFMA A-fragment layout (fp16)
//   wb2g[(ky*2+ct)*512 + lane*8 + j] = w2[(ct*16+m)*64 + ci*4 + ky*2 + kx]
//       m=lane&15, k=(lane>>4)*8+j, kx=k>>4, ci=k&15          (2048)
//   wb3g[(ct*4+pos)*512 + lane*8 + j] = w3[(ct*16+m)*128 + ci*4 + pos]
//       m=lane&15, ci=(lane>>4)*8+j                           (8192)
// ---------------------------------------------------------------------------
__global__ void prep_convw(const float* __restrict__ w2, const float* __restrict__ w3,
                           unsigned short* __restrict__ wb2g, unsigned short* __restrict__ wb3g)
{
    const int t = blockIdx.x * 256 + threadIdx.x;     // < 10240
    if (t < 2048) {
        const int j = t & 7, lane = (t >> 3) & 63, f = t >> 9;   // f = ky*2+ct
        const int ky = f >> 1, ct = f & 1;
        const int k = ((lane >> 4) << 3) + j, kx = k >> 4, ci = k & 15;
        wb2g[t] = f2h(w2[(ct * 16 + (lane & 15)) * 64 + ci * 4 + ky * 2 + kx]);
    } else if (t < 10240) {
        const int u = t - 2048;
        const int j = u & 7, lane = (u >> 3) & 63, f = u >> 9;   // f = ct*4+pos
        const int ct = f >> 2, pos = f & 3;
        const int ci = ((lane >> 4) << 3) + j;
        wb3g[u] = f2h(w3[(ct * 16 + (lane & 15)) * 128 + ci * 4 + pos]);
    }
}

// ---------------------------------------------------------------------------
// K1: fused conv. 16 images / block, 2048 blocks, 256 thr (4 waves).
//   LDS strides are odd multiples of 16B => <=2-way bank aliasing (free).
//   u1: obs fp32 [img][148]  ->  c2s fp16 [img][pix(pad 25->25)][32] stride 808
//   u2: c1s fp16 [img][36px][16ci] stride 584 -> c3s fp16 [img][1024+pad8]
// ---------------------------------------------------------------------------
__global__ __launch_bounds__(256, 2) void conv_fused(
    const float* __restrict__ obs,
    const float* __restrict__ w1, const float* __restrict__ b1,
    const float* __restrict__ b2, const float* __restrict__ b3,
    const unsigned short* __restrict__ wb2g,
    const unsigned short* __restrict__ wb3g,
    unsigned short* __restrict__ featb)
{
    __shared__ __align__(16) unsigned char u1[25856];   // max(obs 9472, c2s 25856)
    __shared__ __align__(16) unsigned char u2[33024];   // max(c1s 18688, c3s 33024)
    __shared__ float w1s[192];
    __shared__ float b1s[16];

    float* s_obs = (float*)u1;                 // [img][148]
    unsigned short* c2s = (unsigned short*)u1; // [img][pix*32+ci], img stride 808
    unsigned short* c1s = (unsigned short*)u2; // [img][p*16+ci],  img stride 584
    unsigned short* c3s = (unsigned short*)u2; // [img][p*64+co],  img stride 1032

    const int tid = threadIdx.x, lane = tid & 63, wv = tid >> 6;
    const int base = blockIdx.x * 16;

    if (tid < 192) w1s[tid] = w1[tid];
    if (tid < 16)  b1s[tid] = b1[tid];
    for (int i = tid; i < 16 * 147; i += 256) {
        const int im = i / 147, r = i - im * 147;
        s_obs[im * 148 + r] = obs[(size_t)(base + im) * 147 + r];
    }
    __syncthreads();

    // ---- conv1 (fp32 VALU): thread=(img, p) -> c1s[img][p][ci0..15] fp16 ----
    {
        const int img = tid & 15;
        const float* ob = &s_obs[img * 148];
        for (int p = tid >> 4; p < 36; p += 16) {
            const int py = p / 6, px = p % 6;
            float o[12];
#pragma unroll
            for (int ky = 0; ky < 2; ky++)
#pragma unroll
                for (int kx = 0; kx < 2; kx++)
#pragma unroll
                    for (int cc = 0; cc < 3; cc++)
                        o[cc * 4 + ky * 2 + kx] = ob[((py + ky) * 7 + px + kx) * 3 + cc];
            unsigned short res[16];
#pragma unroll
            for (int ci = 0; ci < 16; ci++) {
                float a = b1s[ci];
#pragma unroll
                for (int q = 0; q < 12; q++) a = fmaf(o[q], w1s[ci * 12 + q], a);
                res[ci] = f2h(fmaxf(a, 0.0f));
            }
            *(ushort8v*)&c1s[img * 584 + p * 16]     = *(ushort8v*)&res[0];
            *(ushort8v*)&c1s[img * 584 + p * 16 + 8] = *(ushort8v*)&res[8];
        }
    }
    __syncthreads();

    // ---- conv2 (MFMA): site=(p, cotile); A=weights(M=co16), B=imgs(N=16) ----
    {
        const int ct = wv & 1, par = wv >> 1;
        const int img = lane & 15, kq = lane >> 4;
        f16x8 wA[2];
        wA[0] = *(const f16x8*)&wb2g[(0 + ct) * 512 + lane * 8];   // ky=0
        wA[1] = *(const f16x8*)&wb2g[(2 + ct) * 512 + lane * 8];   // ky=1
        const float4 b2v = *(const float4*)&b2[ct * 16 + kq * 4];
#pragma unroll 2
        for (int p = par; p < 25; p += 2) {
            const int py = p / 5, px = p % 5;
            f32x4 acc = {0.f, 0.f, 0.f, 0.f};
#pragma unroll
            for (int ky = 0; ky < 2; ky++) {
                const int pix = (py + ky) * 6 + px + (kq >> 1);
                const f16x8 bv = *(const f16x8*)&c1s[img * 584 + pix * 16 + (kq & 1) * 8];
                acc = __builtin_amdgcn_mfma_f32_16x16x32_f16(wA[ky], bv, acc, 0, 0, 0);
            }
            unsigned short r4[4];
            r4[0] = f2h(fmaxf(acc[0] + b2v.x, 0.0f));
            r4[1] = f2h(fmaxf(acc[1] + b2v.y, 0.0f));
            r4[2] = f2h(fmaxf(acc[2] + b2v.z, 0.0f));
            r4[3] = f2h(fmaxf(acc[3] + b2v.w, 0.0f));
            *(ushort4v*)&c2s[img * 808 + p * 32 + ct * 16 + kq * 4] = *(ushort4v*)&r4[0];
        }
    }
    __syncthreads();

    // ---- conv3 (MFMA): wave = cotile (4 x 16 co); 16 pixel-sites each ----
    {
        const int ct = wv;
        const int img = lane & 15, kq = lane >> 4;
        f16x8 wA3[4];
#pragma unroll
        for (int pos = 0; pos < 4; pos++)
            wA3[pos] = *(const f16x8*)&wb3g[(ct * 4 + pos) * 512 + lane * 8];
        const float4 b3v = *(const float4*)&b3[ct * 16 + kq * 4];
#pragma unroll 4
        for (int p = 0; p < 16; p++) {
            const int py = p >> 2, px = p & 3;
            f32x4 acc = {0.f, 0.f, 0.f, 0.f};
#pragma unroll
            for (int pos = 0; pos < 4; pos++) {
                const int pix = (py + (pos >> 1)) * 5 + px + (pos & 1);
                const f16x8 bv = *(const f16x8*)&c2s[img * 808 + pix * 32 + kq * 8];
                acc = __builtin_amdgcn_mfma_f32_16x16x32_f16(wA3[pos], bv, acc, 0, 0, 0);
            }
            unsigned short r4[4];
            r4[0] = f2h(fmaxf(acc[0] + b3v.x, 0.0f));
            r4[1] = f2h(fmaxf(acc[1] + b3v.y, 0.0f));
            r4[2] = f2h(fmaxf(acc[2] + b3v.z, 0.0f));
            r4[3] = f2h(fmaxf(acc[3] + b3v.w, 0.0f));
            *(ushort4v*)&c3s[img * 1032 + p * 64 + ct * 16 + kq * 4] = *(ushort4v*)&r4[0];
        }
    }
    __syncthreads();

    // ---- dump c3s -> featb (feat row already in permuted k'=p*64+co order) ----
#pragma unroll
    for (int i = 0; i < 8; i++) {
        const int gi = i * 2048 + tid * 8;
        const int img = gi >> 10, flat = gi & 1023;
        *(ushort8v*)&featb[(size_t)(base + img) * 1024 + flat] =
            *(const ushort8v*)&c3s[img * 1032 + flat];
    }
}

// ---------------------------------------------------------------------------
// K3: xproj[32768,512] = featb[32768,1024]_f16 @ wb[512,1024]_f16^T (fp32 out)
//   m97 structure: 128x128 tile, BK=32, 4 waves, 4x4 16x16x32 MFMAs.
// ---------------------------------------------------------------------------
__global__ __launch_bounds__(256, 2) void gemm_xproj_mfma(
    const unsigned short* __restrict__ A,
    const unsigned short* __restrict__ W,
    float* __restrict__ C)
{
    __shared__ unsigned short As[128 * 32];
    __shared__ unsigned short Bs[128 * 32];

    const int tid  = threadIdx.x;
    const int bx = blockIdx.x & 3;
    const int by = blockIdx.x >> 2;
    const int m0 = by * 128, n0 = bx * 128;
    const int lane = tid & 63, wave = tid >> 6;
    const int wm = (wave >> 1) * 64, wn = (wave & 1) * 64;
    const int srow = tid >> 2, sseg = tid & 3;

    const unsigned short* Ag = A + (size_t)(m0 + srow) * 1024 + sseg * 8;
    const unsigned short* Wg = W + (size_t)(n0 + srow) * 1024 + sseg * 8;

    f32x4 acc[4][4];
#pragma unroll
    for (int i = 0; i < 4; i++)
#pragma unroll
        for (int j = 0; j < 4; j++) acc[i][j] = (f32x4){0.f, 0.f, 0.f, 0.f};

    const int fr = lane & 15, fq = lane >> 4;

    for (int k0 = 0; k0 < 1024; k0 += 32) {
        __syncthreads();
        GLDS16(Ag + k0,             (char*)As + tid * 16);
        GLDS16(Ag + k0 + 64 * 1024, (char*)As + tid * 16 + 4096);
        GLDS16(Wg + k0,             (char*)Bs + tid * 16);
        GLDS16(Wg + k0 + 64 * 1024, (char*)Bs + tid * 16 + 4096);
        __syncthreads();

        f16x8 af[4], bfv[4];
#pragma unroll
        for (int i = 0; i < 4; i++)
            af[i] = *(const f16x8*)&As[(wm + i * 16 + fr) * 32 + fq * 8];
#pragma unroll
        for (int j = 0; j < 4; j++)
            bfv[j] = *(const f16x8*)&Bs[(wn + j * 16 + fr) * 32 + fq * 8];
#pragma unroll
        for (int i = 0; i < 4; i++)
#pragma unroll
            for (int j = 0; j < 4; j++)
                acc[i][j] = __builtin_amdgcn_mfma_f32_16x16x32_f16(af[i], bfv[j], acc[i][j], 0, 0, 0);
    }

    const int cr = fq * 4, cc = fr;
#pragma unroll
    for (int i = 0; i < 4; i++) {
#pragma unroll
        for (int j = 0; j < 4; j++) {
            float* cp = &C[(size_t)(m0 + wm + i * 16 + cr) * 512 + (n0 + wn + j * 16 + cc)];
#pragma unroll
            for (int r = 0; r < 4; r++)
                cp[(size_t)r * 512] = acc[i][j][r];
        }
    }
}

// ---------------------------------------------------------------------------
// K4: LSTM scan. Block b = batch element; 512 thr, thread j owns gate row j.
// ---------------------------------------------------------------------------
__global__ __launch_bounds__(512, 2) void lstm_kernel(
    const float* __restrict__ xproj, const float* __restrict__ done,
    const float* __restrict__ h0, const float* __restrict__ c0,
    const float* __restrict__ w_hh,
    const float* __restrict__ b_ih, const float* __restrict__ b_hh,
    float* __restrict__ hid, float* __restrict__ out)
{
    const int b = blockIdx.x;
    const int j = threadIdx.x;

    __shared__ __align__(16) float h_s[HID];
    __shared__ float a_s[512];

    float w[128];
    const float4* wrow = (const float4*)(w_hh + (size_t)j * 128);
#pragma unroll
    for (int q = 0; q < 32; q++) {
        const float4 v = wrow[q];
        w[q * 4 + 0] = v.x; w[q * 4 + 1] = v.y; w[q * 4 + 2] = v.z; w[q * 4 + 3] = v.w;
    }
    const float bias = b_ih[j] + b_hh[j];

    float h = 0.0f, c = 0.0f;
    if (j < HID) { h = h0[b * HID + j]; c = c0[b * HID + j]; }

    float xp   = xproj[(size_t)b * 512 + j];
    float dcur = done[b];

    for (int t = 0; t < T_LEN; t++) {
        if (j < HID) {
            const float m = 1.0f - dcur;
            h *= m; c *= m;
            h_s[j] = h;
        }
        __syncthreads();

        float g0 = bias + xp, g1 = 0.0f, g2 = 0.0f, g3 = 0.0f;
#pragma unroll
        for (int q = 0; q < 32; q++) {
            const float4 hv = *(const float4*)&h_s[q * 4];
            g0 = fmaf(w[q * 4 + 0], hv.x, g0);
            g1 = fmaf(w[q * 4 + 1], hv.y, g1);
            g2 = fmaf(w[q * 4 + 2], hv.z, g2);
            g3 = fmaf(w[q * 4 + 3], hv.w, g3);
        }
        const float g = (g0 + g1) + (g2 + g3);
        if (t < T_LEN - 1) {
            xp   = xproj[((size_t)(t + 1) * B_ENV + b) * 512 + j];
            dcur = done[(t + 1) * B_ENV + b];
        }

        const float a = (j >= 256 && j < 384) ? tanh_(g) : sigm_(g);
        a_s[j] = a;
        __syncthreads();

        if (j < HID) {
            const float ig = a_s[j], fg = a_s[j + 128], gg = a_s[j + 256], og = a_s[j + 384];
            c = fmaf(fg, c, ig * gg);
            h = og * tanh_(c);
            hid[((size_t)t * B_ENV + b) * HID + j] = h;
        }
    }

    if (j < HID) {
        out[262144 + b * HID + j] = h;
        out[294912 + b * HID + j] = c;
    }
}

// ---------------------------------------------------------------------------
// K5: heads. out[n][0..6] = actor, out[n][7] = critic. 32 rows / block.
// ---------------------------------------------------------------------------
__global__ __launch_bounds__(256, 2) void heads_kernel(
    const float* __restrict__ hid,
    const float* __restrict__ aw, const float* __restrict__ ab,
    const float* __restrict__ cw, const float* __restrict__ cb,
    float* __restrict__ out)
{
    __shared__ float hs[32 * 129];
    __shared__ float ws[8 * 130];
    __shared__ float bs[8];

    const int tid = threadIdx.x;
    const int n0 = blockIdx.x * 32;

    for (int i = tid; i < 1024; i += 256) {
        const int r = i >> 7, k = i & 127;
        ws[r * 130 + k] = (r < 7) ? aw[r * 128 + k] : cw[k];
    }
    if (tid < 8) bs[tid] = (tid < 7) ? ab[tid] : cb[0];
    for (int i = tid; i < 4096; i += 256) {
        const int r = i >> 7, k = i & 127;
        hs[r * 129 + k] = hid[(size_t)(n0 + r) * 128 + k];
    }
    __syncthreads();

    const int r = tid >> 3, jj = tid & 7;
    float acc = bs[jj];
    const float* hp = &hs[r * 129];
    const float* wp = &ws[jj * 130];
#pragma unroll
    for (int k = 0; k < 128; k++) acc = fmaf(hp[k], wp[k], acc);
    out[(size_t)(n0 + r) * 8 + jj] = acc;
}

// ---------------------------------------------------------------------------
extern "C" void kernel_launch(void* const* d_in, const int* in_sizes, int n_in,
                              void* d_out, int out_size, void* d_ws, size_t ws_size,
                              hipStream_t stream)
{
    (void)in_sizes; (void)n_in; (void)out_size; (void)ws_size;

    const float* obs  = (const float*)d_in[0];
    const float* done = (const float*)d_in[1];
    const float* h0   = (const float*)d_in[2];
    const float* c0   = (const float*)d_in[3];
    const float* w1   = (const float*)d_in[4];
    const float* b1   = (const float*)d_in[5];
    const float* w2   = (const float*)d_in[6];
    const float* b2   = (const float*)d_in[7];
    const float* w3   = (const float*)d_in[8];
    const float* b3   = (const float*)d_in[9];
    const float* w_ih = (const float*)d_in[10];
    const float* w_hh = (const float*)d_in[11];
    const float* b_ih = (const float*)d_in[12];
    const float* b_hh = (const float*)d_in[13];
    const float* aw   = (const float*)d_in[14];
    const float* ab   = (const float*)d_in[15];
    const float* cw   = (const float*)d_in[16];
    const float* cb   = (const float*)d_in[17];
    float* out = (float*)d_out;

    unsigned short* featb = (unsigned short*)d_ws;     // 33,554,432 u16
    unsigned short* wb    = featb + 33554432ull;       //    524,288 u16
    unsigned short* wb2g  = wb    + 524288ull;         //      2,048 u16
    unsigned short* wb3g  = wb2g  + 2048ull;           //      8,192 u16
    float* xproj = (float*)(wb3g + 8192ull + 2048ull); // align pad; 16,777,216 f32
    float* hid   = xproj + 16777216ull;                //  4,194,304 f32

    prep_wih<<<2048, 256, 0, stream>>>(w_ih, wb);
    prep_convw<<<40, 256, 0, stream>>>(w2, w3, wb2g, wb3g);
    conv_fused<<<2048, 256, 0, stream>>>(obs, w1, b1, b2, b3, wb2g, wb3g, featb);
    gemm_xproj_mfma<<<1024, 256, 0, stream>>>(featb, wb, xproj);
    lstm_kernel<<<256, 512, 0, stream>>>(xproj, done, h0, c0, w_hh, b_ih, b_hh, hid, out);
    heads_kernel<<<1024, 256, 0, stream>>>(hid, aw, ab, cw, cb, out);
}